// Round 3
// baseline (13433.446 us; speedup 1.0000x reference)
//
#include <hip/hip_runtime.h>
#include <hip/hip_bf16.h>

// ---------------------------------------------------------------------------
// 3-layer LSTM (TF LSTMCell, gates i,j,f,o, forget_bias=1) + 3 heads.
// B=256, S=128, F=128, H=400, 4H=1600.
//
// Strategy:
//   preZ_l = X_l @ Wx_l + b_l   (big MFMA GEMM, parallel over all (b,t))
//   recurrence: persistent kernel, 8 batch-groups x 25 weight-stationary
//   blocks; W_h fragments live in VGPRs for all 128 steps; h broadcast via
//   device-scope flag barrier (25 blocks/group, groups independent).
//   g = blockIdx.x & 7 so each group's 25 blocks land on one XCD under
//   round-robin dispatch (perf heuristic only; correctness is agent-scope).
//
// Workspace layout (total 173,358,080 B ~ 165.4 MiB):
//   xbf   @ 0          :  8,388,608  B  (x cast to bf16)
//   HA    @ 8388608    : 26,214,400  B  (layer output ping)
//   HB    @ 34603008   : 26,214,400  B  (layer output pong)
//   preZ  @ 60817408   : 104,857,600 B  ([32768][1600] bf16)
//   hbuf  @ 165675008  : 409,600     B  ([2][256][400] bf16 h state)
//   wfrag @ 166084608  : 3,276,800   B  (GEMM B fragments, 3 layers)
//   rfrag @ 169361408  : 3,993,600   B  (recurrent B fragments, 3 layers)
//   flags @ 173355008  : 3,072       B  (3 layers x 8 groups x 32 u32)
// ---------------------------------------------------------------------------

typedef __attribute__((ext_vector_type(8))) short bf16x8;  // 8 bf16 = 4 VGPR
typedef __attribute__((ext_vector_type(4))) float f32x4;

#define S_LEN 128
#define HID   400
#define NCOL  1600
#define NCB   25     // blocks per recurrent group
#define KT_REC 13    // ceil(416/32)
#define WS_NEEDED 173358080ull

__device__ __forceinline__ f32x4 mfma16(bf16x8 a, bf16x8 b, f32x4 c) {
  return __builtin_amdgcn_mfma_f32_16x16x32_bf16(a, b, c, 0, 0, 0);
}
__device__ __forceinline__ void gll16(const void* g, void* l) {
  __builtin_amdgcn_global_load_lds(
      (const __attribute__((address_space(1))) void*)g,
      (__attribute__((address_space(3))) void*)l, 16, 0, 0);
}
__device__ __forceinline__ float bf2f(__hip_bfloat16 h) { return __bfloat162float(h); }
__device__ __forceinline__ __hip_bfloat16 f2bf(float f) { return __float2bfloat16(f); }
__device__ __forceinline__ float sigm(float x) { return 1.f / (1.f + __expf(-x)); }
__device__ __forceinline__ float tanh_fast(float x) { return 1.f - 2.f / (__expf(2.f * x) + 1.f); }

// ---------------------------------------------------------------- cvt x->bf16
__global__ __launch_bounds__(256) void cvt_x_kernel(const float* __restrict__ x,
                                                    __hip_bfloat16* __restrict__ xbf) {
  const int i = blockIdx.x * 256 + threadIdx.x;  // 1,048,576 float4s exactly
  float4 v = ((const float4*)x)[i];
  ushort4 u;
  u.x = __builtin_bit_cast(unsigned short, f2bf(v.x));
  u.y = __builtin_bit_cast(unsigned short, f2bf(v.y));
  u.z = __builtin_bit_cast(unsigned short, f2bf(v.z));
  u.w = __builtin_bit_cast(unsigned short, f2bf(v.w));
  ((ushort4*)xbf)[i] = u;
}

// ---------------------------------------------- weight prep: GEMM B fragments
// wfrag chunks: L0 kt0..3 (K=128), L1 kt0..13 (K=448 pad0), L2 kt0..13.
// chunk(kt,nt) = 64 lanes x 8 bf16; lane l holds W[kt*32+(l>>4)*8+j][nt*16+(l&15)]
__global__ __launch_bounds__(256) void prep_gemm_frag(
    const float* __restrict__ K0, const float* __restrict__ K1,
    const float* __restrict__ K2, __hip_bfloat16* __restrict__ wfrag) {
  const int total = 3200 * 512;
  for (int e = blockIdx.x * 256 + threadIdx.x; e < total; e += gridDim.x * 256) {
    const int ch = e >> 9, r = e & 511;
    const int c16 = r & 15, j = (r >> 4) & 7, kg = r >> 7;
    const float* W; int Kv, chL;
    if (ch < 400)       { W = K0; Kv = 128; chL = ch; }
    else if (ch < 1800) { W = K1; Kv = 400; chL = ch - 400; }
    else                { W = K2; Kv = 400; chL = ch - 1800; }
    const int kt = chL / 100, nt = chL - kt * 100;
    const int k = kt * 32 + kg * 8 + j;
    const float v = (k < Kv) ? W[(long)k * NCOL + nt * 16 + c16] : 0.f;
    wfrag[(ch << 9) + ((kg * 16 + c16) << 3) + j] = f2bf(v);
  }
}

// ------------------------------------------- weight prep: recurrent fragments
// per layer: [cb 25][kt 13][gate 4] chunks; lane l holds
// Wh[kt*32+(l>>4)*8+j][gate*400 + cb*16 + (l&15)]  (Wh rows = kernel rows D..D+399)
__global__ __launch_bounds__(256) void prep_rec_frag(
    const float* __restrict__ K0, const float* __restrict__ K1,
    const float* __restrict__ K2, __hip_bfloat16* __restrict__ rfrag) {
  const int perL = 25 * 52 * 512;  // 665,600 elements
  const int total = 3 * perL;
  for (int e = blockIdx.x * 256 + threadIdx.x; e < total; e += gridDim.x * 256) {
    const int l = e / perL, eL = e - l * perL;
    const int ch = eL >> 9, r = eL & 511;
    const int c16 = r & 15, j = (r >> 4) & 7, kg = r >> 7;
    const int cb = ch / 52, rem = ch - cb * 52;
    const int kt = rem >> 2, w = rem & 3;
    const int k = kt * 32 + kg * 8 + j;
    const int col = w * 400 + cb * 16 + c16;
    const float* W = (l == 0) ? K0 : ((l == 1) ? K1 : K2);
    const int D = (l == 0) ? 128 : 400;
    const float v = (k < HID) ? W[(long)(D + k) * NCOL + col] : 0.f;
    rfrag[(long)l * perL + (ch << 9) + ((kg * 16 + c16) << 3) + j] = f2bf(v);
  }
}

// ------------------------------------------------------------- preZ GEMM
// C[32768][1600] bf16 = A[32768][lda] bf16 @ Wfrag + bias. 128x128 tile,
// BK=64, 4 waves (2x2), fragment-linear LDS staged via global_load_lds x16.
__global__ __launch_bounds__(256) void gemm_kernel(
    const __hip_bfloat16* __restrict__ A, int lda, int kIters,
    const __hip_bfloat16* __restrict__ wfrag, const float* __restrict__ bias,
    __hip_bfloat16* __restrict__ C) {
  __shared__ uint4 lds4[32 * 64];  // 32 KiB: chunks 0-15 A, 16-31 B
  char* lds = (char*)lds4;
  const int tid = threadIdx.x;
  const int wave = tid >> 6, lane = tid & 63;
  const int wm = wave >> 1, wn = wave & 1;
  const int m0 = blockIdx.x << 7, n0 = blockIdx.y << 7;

  f32x4 acc[4][4];
#pragma unroll
  for (int i = 0; i < 4; ++i)
#pragma unroll
    for (int j = 0; j < 4; ++j) acc[i][j] = (f32x4){0.f, 0.f, 0.f, 0.f};

  for (int it = 0; it < kIters; ++it) {
    const int k0 = it << 6;
#pragma unroll
    for (int q = 0; q < 8; ++q) {
      const int id = wave * 8 + q;
      char* dst = lds + (id << 10);
      if (id < 16) {  // A chunk (kk, mt)
        const int kk = id >> 3, mt = id & 7;
        const int m = m0 + mt * 16 + (lane & 15);
        int k = k0 + kk * 32 + ((lane >> 4) << 3);
        if (k + 8 > lda) k = 0;  // garbage x zero-B is safe
        gll16((const char*)A + (((long)m * lda + k) << 1), dst);
      } else {        // B chunk (kk, nt)
        const int kk = (id >> 3) & 1, nt = id & 7;
        const int ktg = (it << 1) + kk;
        int ntg = (n0 >> 4) + nt;
        if (ntg > 99) ntg = 99;  // results discarded by store guard
        gll16((const char*)wfrag + ((((ktg * 100 + ntg) << 6) + lane) << 4), dst);
      }
    }
    asm volatile("s_waitcnt vmcnt(0)" ::: "memory");
    __syncthreads();
#pragma unroll
    for (int kk = 0; kk < 2; ++kk) {
      bf16x8 af[4], bfr[4];
#pragma unroll
      for (int i = 0; i < 4; ++i) {
        af[i]  = *(const bf16x8*)(lds + ((kk * 8 + wm * 4 + i) << 10) + (lane << 4));
        bfr[i] = *(const bf16x8*)(lds + ((16 + kk * 8 + wn * 4 + i) << 10) + (lane << 4));
      }
#pragma unroll
      for (int i = 0; i < 4; ++i)
#pragma unroll
        for (int j = 0; j < 4; ++j) acc[i][j] = mfma16(af[i], bfr[j], acc[i][j]);
    }
    __syncthreads();
  }
  const int rowbase = m0 + wm * 64 + ((lane >> 4) << 2);
  const int colbase = n0 + wn * 64 + (lane & 15);
#pragma unroll
  for (int j = 0; j < 4; ++j) {
    const int col = colbase + j * 16;
    if (col < NCOL) {
      const float bs = bias[col];
#pragma unroll
      for (int i = 0; i < 4; ++i) {
        const int row = rowbase + i * 16;
#pragma unroll
        for (int r = 0; r < 4; ++r)
          C[(long)(row + r) * NCOL + col] = f2bf(acc[i][j][r] + bs);
      }
    }
  }
}

// ------------------------------------------------------------- recurrence
// grid = 200 blocks = 8 groups x 25 blocks. Group g owns batch rows
// g*32..g*32+31; block cb owns hidden units cb*16..cb*16+15 (all 4 gates).
// Wave w = gate w; its 13 B fragments stay in VGPRs for all 128 steps.
__global__ __launch_bounds__(256) void rec_kernel(
    const __hip_bfloat16* __restrict__ rfrag,  // this layer's fragment seg
    const __hip_bfloat16* __restrict__ preZ,   // [32768][1600] bf16
    __hip_bfloat16* __restrict__ Hout,         // [32768][400] bf16
    __hip_bfloat16* __restrict__ hbuf,         // [2][256][400] bf16
    unsigned* __restrict__ flags) {            // [8][32] u32, zeroed
  __shared__ uint4 AldsV[26 * 64];     // 26 KiB: [kt][mt] chunks
  __shared__ float zlds[4 * 32 * 16];  // 8 KiB: [gate][row32][unit16]
  char* Alds = (char*)AldsV;

  const int g = blockIdx.x & 7;
  const int cB = blockIdx.x >> 3;
  const int tid = threadIdx.x;
  const int wave = tid >> 6, lane = tid & 63;

  // B fragments -> VGPRs (stationary across all steps)
  bf16x8 breg[KT_REC];
#pragma unroll
  for (int kt = 0; kt < KT_REC; ++kt) {
    uint4 u = ((const uint4*)rfrag)[((cB * KT_REC + kt) * 4 + wave) * 64 + lane];
    breg[kt] = __builtin_bit_cast(bf16x8, u);
  }

  float cst0 = 0.f, cst1 = 0.f;  // c-state: thread = (unit u16, rows r0/r0+16)
  const int u16 = tid & 15, r0 = tid >> 4;

  for (int t = 0; t < S_LEN; ++t) {
    const int p = t & 1;

    // ---- HOISTED preZ loads: issue before staging/MFMA so the ~600-900 cyc
    // HBM/L3 latency hides under the step's LDS staging + MFMA + barrier.
    const int b0r = g * 32 + r0;
    const long pz0 = ((long)b0r * S_LEN + t) * NCOL + cB * 16 + u16;
    const long pz1 = ((long)(b0r + 16) * S_LEN + t) * NCOL + cB * 16 + u16;
    const float pzi0 = bf2f(preZ[pz0]);
    const float pzj0 = bf2f(preZ[pz0 + 400]);
    const float pzf0 = bf2f(preZ[pz0 + 800]);
    const float pzo0 = bf2f(preZ[pz0 + 1200]);
    const float pzi1 = bf2f(preZ[pz1]);
    const float pzj1 = bf2f(preZ[pz1 + 400]);
    const float pzf1 = bf2f(preZ[pz1 + 800]);
    const float pzo1 = bf2f(preZ[pz1 + 1200]);

    // stage A (h tile) fragments: 26 chunks via global_load_lds
    for (int cc = wave; cc < 26; cc += 4) {
      const int kt = cc >> 1, mt = cc & 1;
      const int b = g * 32 + mt * 16 + (lane & 15);
      int k = kt * 32 + ((lane >> 4) << 3);
      if (k >= HID) k = 0;  // pad lanes: garbage x zero-B
      gll16((const char*)hbuf + (((p * 256 + b) * HID + k) << 1), Alds + (cc << 10));
    }
    asm volatile("s_waitcnt vmcnt(0)" ::: "memory");
    __syncthreads();

    f32x4 acc0 = (f32x4){0.f, 0.f, 0.f, 0.f}, acc1 = acc0;
#pragma unroll
    for (int kt = 0; kt < KT_REC; ++kt) {
      bf16x8 a0 = *(const bf16x8*)(Alds + ((kt * 2 + 0) << 10) + (lane << 4));
      bf16x8 a1 = *(const bf16x8*)(Alds + ((kt * 2 + 1) << 10) + (lane << 4));
      acc0 = mfma16(a0, breg[kt], acc0);
      acc1 = mfma16(a1, breg[kt], acc1);
    }
    {
      const int colz = lane & 15, rb = (lane >> 4) << 2;
#pragma unroll
      for (int r = 0; r < 4; ++r) {
        zlds[(wave * 32 + rb + r) * 16 + colz] = acc0[r];
        zlds[(wave * 32 + rb + r + 16) * 16 + colz] = acc1[r];
      }
    }
    __syncthreads();

    // gate math; c in registers; write h (bf16) to hbuf[next] and Hout
#pragma unroll
    for (int half = 0; half < 2; ++half) {
      const int row = r0 + half * 16;
      const int b = g * 32 + row;
      const long mrow = (long)b * S_LEN + t;
      const float zi = zlds[(0 * 32 + row) * 16 + u16] + (half ? pzi1 : pzi0);
      const float zj = zlds[(1 * 32 + row) * 16 + u16] + (half ? pzj1 : pzj0);
      const float zf = zlds[(2 * 32 + row) * 16 + u16] + (half ? pzf1 : pzf0) + 1.f;
      const float zo = zlds[(3 * 32 + row) * 16 + u16] + (half ? pzo1 : pzo0);
      float c_old = half ? cst1 : cst0;
      const float cn = c_old * sigm(zf) + sigm(zi) * tanh_fast(zj);
      if (half) cst1 = cn; else cst0 = cn;
      const float hv = tanh_fast(cn) * sigm(zo);
      const __hip_bfloat16 hb16 = f2bf(hv);
      Hout[mrow * HID + cB * 16 + u16] = hb16;
      hbuf[((1 - p) * 256 + b) * HID + cB * 16 + u16] = hb16;
    }
    __threadfence();   // publish this thread's h-writes at agent scope
    __syncthreads();
    if (t == S_LEN - 1) break;

    // group barrier: flag store + 25-lane parallel poll (device scope)
    const unsigned tgt = (unsigned)(t + 1);
    if (tid == 0)
      __hip_atomic_store(&flags[g * 32 + cB], tgt, __ATOMIC_RELEASE,
                         __HIP_MEMORY_SCOPE_AGENT);
    if (wave == 0) {
      while (true) {
        unsigned v = tgt;
        if (lane < NCB)
          v = __hip_atomic_load(&flags[g * 32 + lane], __ATOMIC_ACQUIRE,
                                __HIP_MEMORY_SCOPE_AGENT);
        if (__all((int)(v >= tgt))) break;
        __builtin_amdgcn_s_sleep(2);
      }
    }
    __syncthreads();
    __threadfence();   // conservative: ensure no stale h served to next step
  }
}

// ------------------------------------------------------------- output heads
__global__ __launch_bounds__(256) void heads_kernel(
    const __hip_bfloat16* __restrict__ H, const float* __restrict__ wlg,
    const float* __restrict__ blg, const float* __restrict__ wsm2,
    const float* __restrict__ bsm2, const float* __restrict__ w5,
    const float* __restrict__ b5, float* __restrict__ out) {
  __shared__ float wc[8][400];
  const int tid = threadIdx.x;
  for (int e = tid; e < 3200; e += 256) {
    const int cc = e / 400, k = e - cc * 400;
    float v;
    if (cc == 0) v = wlg[k];
    else if (cc <= 2) v = wsm2[k * 2 + (cc - 1)];
    else v = w5[k * 5 + (cc - 3)];
    wc[cc][k] = v;
  }
  __syncthreads();
  const int wave = tid >> 6, lane = tid & 63;
  const int row = blockIdx.x * 4 + wave;
  const __hip_bfloat16* hrow = H + (long)row * HID;
  float pacc[8] = {0.f, 0.f, 0.f, 0.f, 0.f, 0.f, 0.f, 0.f};
  for (int k = lane; k < HID; k += 64) {
    const float hv = bf2f(hrow[k]);
#pragma unroll
    for (int cc = 0; cc < 8; ++cc) pacc[cc] += hv * wc[cc][k];
  }
#pragma unroll
  for (int cc = 0; cc < 8; ++cc)
    for (int off = 32; off > 0; off >>= 1)
      pacc[cc] += __shfl_xor(pacc[cc], off, 64);
  if (lane == 0) {
    const float o0 = sigm(pacc[0] + blg[0]);
    const float z1 = pacc[1] + bsm2[0], z2 = pacc[2] + bsm2[1];
    const float mm = fmaxf(z1, z2);
    const float e1 = __expf(z1 - mm), e2 = __expf(z2 - mm);
    const float inv2 = 1.f / (e1 + e2);
    float z5[5], m5 = -1e30f;
#pragma unroll
    for (int c = 0; c < 5; ++c) { z5[c] = pacc[3 + c] + b5[c]; m5 = fmaxf(m5, z5[c]); }
    float es[5], s5 = 0.f;
#pragma unroll
    for (int c = 0; c < 5; ++c) { es[c] = __expf(z5[c] - m5); s5 += es[c]; }
    const float inv5 = 1.f / s5;
    float4* op = (float4*)(out + (long)row * 8);
    op[0] = make_float4(o0, e1 * inv2, e2 * inv2, es[0] * inv5);
    op[1] = make_float4(es[1] * inv5, es[2] * inv5, es[3] * inv5, es[4] * inv5);
  }
}

// ---------------------------------------------------------------------------
extern "C" void kernel_launch(void* const* d_in, const int* in_sizes, int n_in,
                              void* d_out, int out_size, void* d_ws, size_t ws_size,
                              hipStream_t stream) {
  (void)in_sizes; (void)n_in; (void)out_size;
  // Defensive: if the harness workspace is smaller than our layout, fail
  // cleanly (incorrect output) instead of scribbling out of bounds.
  if (ws_size < WS_NEEDED) return;

  const float* x    = (const float*)d_in[0];
  const float* K0   = (const float*)d_in[1];
  const float* B0   = (const float*)d_in[2];
  const float* K1   = (const float*)d_in[3];
  const float* B1   = (const float*)d_in[4];
  const float* K2   = (const float*)d_in[5];
  const float* B2   = (const float*)d_in[6];
  const float* wlg  = (const float*)d_in[7];
  const float* blg  = (const float*)d_in[8];
  const float* wsm2 = (const float*)d_in[9];
  const float* bsm2 = (const float*)d_in[10];
  const float* w5   = (const float*)d_in[11];
  const float* b5   = (const float*)d_in[12];
  float* out = (float*)d_out;
  char* ws = (char*)d_ws;

  __hip_bfloat16* xbf   = (__hip_bfloat16*)(ws + 0);
  __hip_bfloat16* HA    = (__hip_bfloat16*)(ws + 8388608);
  __hip_bfloat16* HB    = (__hip_bfloat16*)(ws + 34603008);
  __hip_bfloat16* preZ  = (__hip_bfloat16*)(ws + 60817408);
  __hip_bfloat16* hbuf  = (__hip_bfloat16*)(ws + 165675008);
  __hip_bfloat16* wfrag = (__hip_bfloat16*)(ws + 166084608);
  __hip_bfloat16* rfrag = (__hip_bfloat16*)(ws + 169361408);
  unsigned* flags       = (unsigned*)(ws + 173355008);

  hipMemsetAsync(flags, 0, 3072, stream);
  hipMemsetAsync(hbuf, 0, 204800, stream);  // h(t=-1) = 0  (parity-0 buffer)
  cvt_x_kernel<<<4096, 256, 0, stream>>>(x, xbf);
  prep_gemm_frag<<<2048, 256, 0, stream>>>(K0, K1, K2, wfrag);
  prep_rec_frag<<<2048, 256, 0, stream>>>(K0, K1, K2, rfrag);

  // layer 0
  gemm_kernel<<<dim3(256, 13), 256, 0, stream>>>(xbf, 128, 2, wfrag, B0, preZ);
  rec_kernel<<<200, 256, 0, stream>>>(rfrag, preZ, HA, hbuf, flags);

  // layer 1
  hipMemsetAsync(hbuf, 0, 204800, stream);
  gemm_kernel<<<dim3(256, 13), 256, 0, stream>>>(HA, 400, 7, wfrag + 204800, B1, preZ);
  rec_kernel<<<200, 256, 0, stream>>>(rfrag + 665600, preZ, HB, hbuf, flags + 256);

  // layer 2
  hipMemsetAsync(hbuf, 0, 204800, stream);
  gemm_kernel<<<dim3(256, 13), 256, 0, stream>>>(HB, 400, 7, wfrag + 921600, B2, preZ);
  rec_kernel<<<200, 256, 0, stream>>>(rfrag + 1331200, preZ, HA, hbuf, flags + 512);

  // heads (layer-2 output is in HA)
  heads_kernel<<<8192, 256, 0, stream>>>(HA, wlg, blg, wsm2, bsm2, w5, b5, out);
}